// Round 11
// baseline (323.881 us; speedup 1.0000x reference)
//
#include <hip/hip_runtime.h>
#include <hip/hip_bf16.h>

// Problem: B=4, N=2048, H=16, Dh=64, D=1024. All global tensors fp32.
// out = LN( softmax(Q K^T / 8) V @ W_out^T ) * g   (fp32 out).
// R17: proj+LN fused into one LDS-free kernel. Block = 512 thr (8 waves)
// owns 32 FULL rows x 1024 cols (grid 256): A/W fragments loaded directly
// from global (W 2MB = L2-resident per XCD; per-instr pattern = 16 rows x
// 64B full lines). K-order identical to old proj -> GEMM bit-identical.
// LN fused in epilogue: shfl_xor intra-group reduce + 2KB LDS cross-wave
// reduce, write out once. Eliminates ln kernel + 64MB of C round-trip.
// attn/prep unchanged from R16 (verified 272us, attn 122us).

#define Bv 4
#define Nv 2048
#define Hv 16
#define DHv 64
#define Dv 1024
#define NT (Nv / 64)

#define KCONV_BLOCKS 4096
#define WCONV_BLOCKS 512
#define VT_BLOCKS 2048

#define L2E 1.44269504088896340736f

typedef __attribute__((ext_vector_type(8))) short short8;
typedef __attribute__((ext_vector_type(4))) float floatx4;

// bf16 pair pack, round-half-up (+0x8000 then take high16 via one v_perm_b32).
__device__ inline unsigned pack_bf2(float a, float b) {
    unsigned ua = __builtin_bit_cast(unsigned, a) + 0x8000u;
    unsigned ub = __builtin_bit_cast(unsigned, b) + 0x8000u;
    return __builtin_amdgcn_perm(ub, ua, 0x07060302u);  // [b.hi16 : a.hi16]
}

// Packed f32->bf16x2 convert, RTE (1 VALU instr). dst = [bf16(b) : bf16(a)].
__device__ inline unsigned cvt_pk_bf16(float a, float b) {
    unsigned d;
    asm("v_cvt_pk_bf16_f32 %0, %1, %2" : "=v"(d) : "v"(a), "v"(b));
    return d;
}

// RTE bf16 pair (epilogue, grouped for 8B stores).
__device__ inline unsigned bf2u_rte(float a, float b) {
    unsigned short ua = __builtin_bit_cast(unsigned short, __float2bfloat16(a));
    unsigned short ub = __builtin_bit_cast(unsigned short, __float2bfloat16(b));
    return (unsigned)ua | ((unsigned)ub << 16);
}

// 3-input max; clang fuses nested fmaxf to v_max3_f32 on gfx9+.
__device__ inline float max3f(float a, float b, float c) {
    return fmaxf(fmaxf(a, b), c);
}

__device__ inline void plswap16(unsigned &a, unsigned &b) {
    auto r = __builtin_amdgcn_permlane16_swap(a, b, false, false);
    a = r[0]; b = r[1];
}
__device__ inline void plswap32(unsigned &a, unsigned &b) {
    auto r = __builtin_amdgcn_permlane32_swap(a, b, false, false);
    a = r[0]; b = r[1];
}

// Cross-quad max via permlane self-swap (== shfl_xor 16 then 32).
__device__ inline float redq_max(float x) {
    unsigned a = __builtin_bit_cast(unsigned, x), b = a;
    plswap16(a, b);
    float m = fmaxf(__builtin_bit_cast(float, a), __builtin_bit_cast(float, b));
    unsigned c = __builtin_bit_cast(unsigned, m), d = c;
    plswap32(c, d);
    return fmaxf(__builtin_bit_cast(float, c), __builtin_bit_cast(float, d));
}

// ---------------------------------------------------------------------------
// Fused prep (one launch): K f32->bf16 (4096 blk), W f32->bf16 (512 blk),
// V f32 -> V^T bf16 [b][h][64][2048] (2048 blk). pack_bf2 rounding keeps all
// downstream operand bits identical.
// ---------------------------------------------------------------------------
__global__ __launch_bounds__(256)
void prep_all(const float* __restrict__ K, __hip_bfloat16* __restrict__ Kb,
              const float* __restrict__ W, __hip_bfloat16* __restrict__ Wb,
              const float* __restrict__ v, __hip_bfloat16* __restrict__ vt) {
    __shared__ short T[64][76];   // vtrans scratch (+12 pad)
    int bid = blockIdx.x;
    if (bid < KCONV_BLOCKS + WCONV_BLOCKS) {
        const float* src;
        __hip_bfloat16* dst;
        if (bid < KCONV_BLOCKS) { src = K; dst = Kb; }
        else { src = W; dst = Wb; bid -= KCONV_BLOCKS; }
        int base = (bid * 256 + threadIdx.x) * 8;
        float4 f0 = *(const float4*)(src + base);
        float4 f1 = *(const float4*)(src + base + 4);
        uint4 u;
        u.x = pack_bf2(f0.x, f0.y);
        u.y = pack_bf2(f0.z, f0.w);
        u.z = pack_bf2(f1.x, f1.y);
        u.w = pack_bf2(f1.z, f1.w);
        *(uint4*)(dst + base) = u;
        return;
    }
    bid -= KCONV_BLOCKS + WCONV_BLOCKS;        // 0..2047
    const int b = bid >> 9;                    // 512 per batch
    const int rem = bid & 511;
    const int h = rem >> 5;                    // 16 heads
    const int n0 = (rem & 31) * 64;            // 32 n-tiles
    const int t = threadIdx.x;
    const int ir = t >> 4;
    const int d4 = (t & 15) * 4;
#pragma unroll
    for (int pass = 0; pass < 4; ++pass) {
        int n = pass * 16 + ir;
        float4 f = *(const float4*)(v + ((size_t)b * Nv + n0 + n) * Dv + h * DHv + d4);
        T[d4 + 0][n] = (short)(pack_bf2(f.x, f.x) & 0xffffu);
        T[d4 + 1][n] = (short)(pack_bf2(f.y, f.y) & 0xffffu);
        T[d4 + 2][n] = (short)(pack_bf2(f.z, f.z) & 0xffffu);
        T[d4 + 3][n] = (short)(pack_bf2(f.w, f.w) & 0xffffu);
    }
    __syncthreads();
    const int d = t >> 2, kg = (t & 3) * 16;
    unsigned u[8];
#pragma unroll
    for (int i = 0; i < 8; ++i)
        u[i] = (unsigned)(unsigned short)T[d][kg + 2 * i] |
               ((unsigned)(unsigned short)T[d][kg + 2 * i + 1] << 16);
    __hip_bfloat16* op = vt + ((size_t)(b * Hv + h) * DHv + d) * Nv + n0 + kg;
    *(uint4*)op = *(uint4*)&u[0];
    *(uint4*)(op + 8) = *(uint4*)&u[4];
}

// ---------------------------------------------------------------------------
// MFMA flash attention, prep-fed, O^T accumulation. QBLK=64: block = 256 thr
// (4 waves) = 64 queries of one (b,h); wave owns 16 queries (lane = query).
// K / V^T staged via global_load_lds w16 (source-side inverse XOR swizzle).
// Softmax cross-lane via permlane; alpha/linv lane-local (O^T). l computed
// by ones-row MFMA; P packed with v_cvt_pk_bf16_f32.  (Unchanged from R16.)
// ---------------------------------------------------------------------------
__global__ __launch_bounds__(256, 8)
void attn_mfma_pre(const float* __restrict__ q,
                   const __hip_bfloat16* __restrict__ Kb,
                   const __hip_bfloat16* __restrict__ Vtb,
                   __hip_bfloat16* __restrict__ out) {
    __shared__ __align__(16) short Kt[2][64 * 64];   // 16 KB
    __shared__ __align__(16) short Vt[2][64 * 64];   // 16 KB (V^T: rows = d)

    const int t = threadIdx.x;
    const int wave = t >> 6, lane = t & 63;
    const int quad = lane >> 4, lr = lane & 15;
    const int b = blockIdx.z;
    // bijective XCD swizzle over (qtile,head): same-h blocks -> same XCD.
    const int lid2 = blockIdx.y * 32 + blockIdx.x;   // 0..511
    const int xcd = lid2 & 7, jj = lid2 >> 3;        // jj 0..63
    const int h = xcd * 2 + (jj >> 5);
    const int q0 = (jj & 31) * 64;
    const size_t qbh = ((size_t)b * Nv) * Dv + h * DHv;
    const __hip_bfloat16* kb = Kb + (size_t)b * Nv * Dv + h * DHv;
    const __hip_bfloat16* vtb = Vtb + (size_t)(b * Hv + h) * DHv * Nv;

    const int srow = lane >> 3;   // row within 8-row chunk
    const int sg = lane & 7;      // stored group
    auto stage = [&](int buf, int k0) {
#pragma unroll
        for (int c = 0; c < 2; ++c) {
            int blk = wave * 2 + c;          // 0..7, wave-uniform
            int r = blk * 8 + srow;
            int g = sg ^ (r & 7);            // inverse swizzle on source
            __builtin_amdgcn_global_load_lds(
                (const __attribute__((address_space(1))) unsigned*)(const void*)
                    (kb + (size_t)(k0 + r) * Dv + g * 8),
                (__attribute__((address_space(3))) unsigned*)(void*)&Kt[buf][blk * 512],
                16, 0, 0);
            __builtin_amdgcn_global_load_lds(
                (const __attribute__((address_space(1))) unsigned*)(const void*)
                    (vtb + (size_t)r * Nv + k0 + g * 8),
                (__attribute__((address_space(3))) unsigned*)(void*)&Vt[buf][blk * 512],
                16, 0, 0);
        }
    };

    stage(0, 0);   // K/V tile-0 DMA in flight first

    // ---- Q fragments direct from global (once), scale 0.125 exact ----
    short8 qfrag[2];   // [kh]: Q[q = q0+wave*16+lr][d = 32kh+8quad+j]
#pragma unroll
    for (int kh = 0; kh < 2; ++kh) {
        int row = q0 + wave * 16 + lr;
        const float* qp = q + qbh + (size_t)row * Dv + kh * 32 + quad * 8;
        float4 f0 = *(const float4*)qp;
        float4 f1 = *(const float4*)(qp + 4);
        int4 qi;
        qi.x = (int)pack_bf2(f0.x * 0.125f, f0.y * 0.125f);
        qi.y = (int)pack_bf2(f0.z * 0.125f, f0.w * 0.125f);
        qi.z = (int)pack_bf2(f1.x * 0.125f, f1.y * 0.125f);
        qi.w = (int)pack_bf2(f1.z * 0.125f, f1.w * 0.125f);
        qfrag[kh] = __builtin_bit_cast(short8, qi);
    }

    // ones-row A-fragment: A[m][k] = (m==0) ? 1.0bf16 : 0. m = lane&15.
    short8 ones_f;
    {
        unsigned w = (lr == 0) ? 0x3F803F80u : 0u;
        int4 oi = {(int)w, (int)w, (int)w, (int)w};
        ones_f = __builtin_bit_cast(short8, oi);
    }

    floatx4 o_acc[4] = {};           // O^T: [td]: O[q=lr][d=16td+4quad+r]
    floatx4 lsum = {};               // lsum[0] on lanes 0-15 = l(query=lr)
    float mrow = -INFINITY;          // per-query (lane-local, lr)

#pragma unroll 2
    for (int it = 0; it < NT; ++it) {
        const int cur = it & 1;                  // compile-time under unroll 2
        __syncthreads();                         // vmcnt drained: buf[cur] staged
        if (it + 1 < NT) stage(1 - cur, (it + 1) * 64);   // latency hidden by compute

        // ---- S^T = K·Q^T ----
        floatx4 s_acc[4] = {};
        __builtin_amdgcn_s_setprio(1);
#pragma unroll
        for (int tt = 0; tt < 4; ++tt) {
            int row = tt * 16 + lr;
            short8 kf0 = *(const short8*)&Kt[cur][row * 64 + ((quad ^ (lr & 7)) << 3)];
            short8 kf1 = *(const short8*)&Kt[cur][row * 64 + (((4 + quad) ^ (lr & 7)) << 3)];
            s_acc[tt] = __builtin_amdgcn_mfma_f32_16x16x32_bf16(kf0, qfrag[0], s_acc[tt], 0, 0, 0);
            s_acc[tt] = __builtin_amdgcn_mfma_f32_16x16x32_bf16(kf1, qfrag[1], s_acc[tt], 0, 0, 0);
        }
        __builtin_amdgcn_s_setprio(0);

        // ---- online softmax (defer-max) + P pack ----
        float m0 = max3f(s_acc[0][0], s_acc[0][1], s_acc[0][2]);
        float m1 = max3f(s_acc[0][3], s_acc[1][0], s_acc[1][1]);
        float m2 = max3f(s_acc[1][2], s_acc[1][3], s_acc[2][0]);
        float m3 = max3f(s_acc[2][1], s_acc[2][2], s_acc[2][3]);
        float m4 = max3f(s_acc[3][0], s_acc[3][1], s_acc[3][2]);
        float m5 = max3f(m0, m1, s_acc[3][3]);
        float tmax = redq_max(max3f(m5, max3f(m2, m3, m4), -INFINITY));
        // defer-max: only rescale when some query's max grew past THR=8.
        if (!__all(tmax <= mrow + 8.0f)) {
            float mnew = fmaxf(mrow, tmax);
            float alpha = __expf(mrow - mnew);   // first tile: exp(-inf)=0
            mrow = mnew;
            lsum[0] *= alpha;                    // lane-local (lanes 0-15 carry l)
#pragma unroll
            for (int td = 0; td < 4; ++td)
#pragma unroll
                for (int r2 = 0; r2 < 4; ++r2) o_acc[td][r2] *= alpha;  // lane-local
        }
        float negmc = -(mrow * L2E);
        unsigned p2[8];
#pragma unroll
        for (int tt = 0; tt < 4; ++tt) {
            float p0 = __builtin_amdgcn_exp2f(__builtin_fmaf(s_acc[tt][0], L2E, negmc));
            float p1 = __builtin_amdgcn_exp2f(__builtin_fmaf(s_acc[tt][1], L2E, negmc));
            float pa = __builtin_amdgcn_exp2f(__builtin_fmaf(s_acc[tt][2], L2E, negmc));
            float pb = __builtin_amdgcn_exp2f(__builtin_fmaf(s_acc[tt][3], L2E, negmc));
            p2[tt * 2 + 0] = cvt_pk_bf16(p0, p1);
            p2[tt * 2 + 1] = cvt_pk_bf16(pa, pb);
        }

        // ---- PV as O^T += V^T·P^T: mfma(V_frag, P_frag). P-gather per pair
        // (x,y): swap32 -> a=[x.lo,y.lo] b=[x.hi,y.hi]; swap16 ->
        // a=[x0,x2,y0,y2] b=[x1,x3,y1,y3] == srcA/srcB words.
        // l rides the MFMA pipe: lsum += ones_row . P. ----
#pragma unroll
        for (int kh = 0; kh < 2; ++kh) {
            int tlo = 4 * kh, thi = 4 * kh + 2;
            unsigned a0 = p2[tlo + 0], b0 = p2[thi + 0];
            unsigned a1 = p2[tlo + 1], b1 = p2[thi + 1];
            plswap32(a0, b0);
            plswap16(a0, b0);
            plswap32(a1, b1);
            plswap16(a1, b1);
            int4 afi;
            afi.x = (int)a0;
            afi.y = (int)a1;
            afi.z = (int)b0;
            afi.w = (int)b1;
            short8 af = __builtin_bit_cast(short8, afi);
            __builtin_amdgcn_s_setprio(1);
#pragma unroll
            for (int td = 0; td < 4; ++td) {
                int d = td * 16 + lr;
                short8 vf = *(const short8*)&Vt[cur][d * 64 + (((kh * 4 + quad) ^ (lr & 7)) << 3)];
                o_acc[td] = __builtin_amdgcn_mfma_f32_16x16x32_bf16(vf, af, o_acc[td], 0, 0, 0);
            }
            lsum = __builtin_amdgcn_mfma_f32_16x16x32_bf16(ones_f, af, lsum, 0, 0, 0);
            __builtin_amdgcn_s_setprio(0);
        }
    }

    // ---- epilogue (O^T): lane owns query q = q0+wave*16+lr.
    // l(q) lives in lsum[0] of lane q (quad 0); broadcast via one shfl. ----
    {
        float linv = __shfl(1.f / lsum[0], lr);
        int qrow = q0 + wave * 16 + lr;
        __hip_bfloat16* op = out + ((size_t)(b * Nv + qrow)) * Dv + h * DHv + quad * 4;
#pragma unroll
        for (int td = 0; td < 4; ++td) {
            uint2 w;
            w.x = bf2u_rte(o_acc[td][0] * linv, o_acc[td][1] * linv);
            w.y = bf2u_rte(o_acc[td][2] * linv, o_acc[td][3] * linv);
            *(uint2*)(op + td * 16) = w;
        }
    }
}

// ---------------------------------------------------------------------------
// Stage 2+3 fused: out = LN(A @ Wb^T) * g. Block = 512 thr (8 waves) owns
// 32 FULL rows x 1024 cols (grid 256). LDS-free K-loop: A/W fragments come
// directly from global (W 2MB -> L2-resident per XCD; per instr each wave
// touches 16 rows x 64B = full lines). K ascends in 32-chunks with quad*8
// sub-offset == old proj's (it*64 + ks*32 + quad*8) -> GEMM bit-identical.
// LN: per-lane partials -> shfl_xor reduce over the 16-lane col-group ->
// 2KB LDS cross-wave reduce -> scale by g, single fp32 write of out.
// ---------------------------------------------------------------------------
__global__ __launch_bounds__(512)
void proj_ln_kernel(const __hip_bfloat16* __restrict__ A,
                    const __hip_bfloat16* __restrict__ Wb,
                    const float* __restrict__ g,
                    float* __restrict__ out) {
    __shared__ float red[8][32][2];   // [wave][row][s,sq]
    __shared__ float mi[32][2];       // [row][mean, inv]

    const int t = threadIdx.x;
    const int wave = t >> 6, lane = t & 63;
    const int quad = lane >> 4, lr = lane & 15;
    const int r0 = blockIdx.x * 32;
    const int wc = wave * 128;        // this wave's 128-col slice

    floatx4 acc[2][8] = {};           // [rt][ct]: rows rt*16+quad*4+r, col ct*16+lr

    const __hip_bfloat16* arow0 = A + (size_t)(r0 + lr) * Dv + quad * 8;
    const __hip_bfloat16* arow1 = arow0 + (size_t)16 * Dv;
    const __hip_bfloat16* wrow = Wb + (size_t)(wc + lr) * Dv + quad * 8;

    for (int k0 = 0; k0 < Dv; k0 += 32) {
        short8 af0 = *(const short8*)(arow0 + k0);
        short8 af1 = *(const short8*)(arow1 + k0);
#pragma unroll
        for (int ct = 0; ct < 8; ++ct) {
            short8 wf = *(const short8*)(wrow + (size_t)ct * 16 * Dv + k0);
            acc[0][ct] = __builtin_amdgcn_mfma_f32_16x16x32_bf16(af0, wf, acc[0][ct], 0, 0, 0);
            acc[1][ct] = __builtin_amdgcn_mfma_f32_16x16x32_bf16(af1, wf, acc[1][ct], 0, 0, 0);
        }
    }

    // ---- LN: per-lane row partials over this wave's 128 cols ----
    float s8[2][4], q8[2][4];
#pragma unroll
    for (int rt = 0; rt < 2; ++rt)
#pragma unroll
        for (int r = 0; r < 4; ++r) {
            float s = 0.f, qq = 0.f;
#pragma unroll
            for (int ct = 0; ct < 8; ++ct) {
                float v = acc[rt][ct][r];
                s += v;
                qq = __builtin_fmaf(v, v, qq);
            }
            s8[rt][r] = s;
            q8[rt][r] = qq;
        }
    // reduce across the 16-lane col-group (lr bits 0..3)
#pragma unroll
    for (int m = 1; m <= 8; m <<= 1)
#pragma unroll
        for (int rt = 0; rt < 2; ++rt)
#pragma unroll
            for (int r = 0; r < 4; ++r) {
                s8[rt][r] += __shfl_xor(s8[rt][r], m);
                q8[rt][r] += __shfl_xor(q8[rt][r], m);
            }
    if (lr == 0) {
#pragma unroll
        for (int rt = 0; rt < 2; ++rt)
#pragma unroll
            for (int r = 0; r < 4; ++r) {
                int row = rt * 16 + quad * 4 + r;
                red[wave][row][0] = s8[rt][r];
                red[wave][row][1] = q8[rt][r];
            }
    }
    __syncthreads();
    if (t < 32) {
        float s = 0.f, qq = 0.f;
#pragma unroll
        for (int w = 0; w < 8; ++w) {
            s += red[w][t][0];
            qq += red[w][t][1];
        }
        const float rn = 1.f / (float)Dv;
        float mean = s * rn;
        float var = qq * rn - mean * mean;
        mi[t][0] = mean;
        mi[t][1] = rsqrtf(var + 1e-5f);
    }
    __syncthreads();

    // ---- scale by g and store fp32 out (single write) ----
    float gv[8];
#pragma unroll
    for (int ct = 0; ct < 8; ++ct) gv[ct] = g[wc + ct * 16 + lr];
#pragma unroll
    for (int rt = 0; rt < 2; ++rt)
#pragma unroll
        for (int r = 0; r < 4; ++r) {
            int row = rt * 16 + quad * 4 + r;
            float mean = mi[row][0], inv = mi[row][1];
            float* op = out + (size_t)(r0 + row) * Dv + wc + lr;
#pragma unroll
            for (int ct = 0; ct < 8; ++ct)
                op[ct * 16] = (acc[rt][ct][r] - mean) * inv * gv[ct];
        }
}

// ---------------------------------------------------------------------------
extern "C" void kernel_launch(void* const* d_in, const int* in_sizes, int n_in,
                              void* d_out, int out_size, void* d_ws, size_t ws_size,
                              hipStream_t stream) {
    const float* q = (const float*)d_in[0];
    const float* k = (const float*)d_in[1];
    const float* v = (const float*)d_in[2];
    const float* W = (const float*)d_in[3];
    const float* g = (const float*)d_in[4];
    float* out = (float*)d_out;

    const size_t attnB = (size_t)Bv * Nv * Dv * 2;       // 16 MiB bf16 attn out
    const size_t wbB = (size_t)Dv * Dv * 2;              // 2 MiB bf16 W
    const size_t kbB = (size_t)Bv * Nv * Dv * 2;         // 16 MiB bf16 K

    __hip_bfloat16* attn = (__hip_bfloat16*)d_ws;
    __hip_bfloat16* Wb = (__hip_bfloat16*)((char*)d_ws + attnB);
    __hip_bfloat16* Kb = (__hip_bfloat16*)((char*)d_ws + attnB + wbB);
    __hip_bfloat16* Vtb = (__hip_bfloat16*)((char*)d_ws + attnB + wbB + kbB);

    prep_all<<<KCONV_BLOCKS + WCONV_BLOCKS + VT_BLOCKS, 256, 0, stream>>>(k, Kb, W, Wb, v, Vtb);
    attn_mfma_pre<<<dim3(32, 16, Bv), 256, 0, stream>>>(q, Kb, Vtb, attn);
    proj_ln_kernel<<<(Bv * Nv) / 32, 512, 0, stream>>>(attn, Wb, g, out);
}

// Round 12
// 276.128 us; speedup vs baseline: 1.1729x; 1.1729x over previous
//
#include <hip/hip_runtime.h>
#include <hip/hip_bf16.h>

// Problem: B=4, N=2048, H=16, Dh=64, D=1024. All global tensors fp32.
// out = LN( softmax(Q K^T / 8) V @ W_out^T ) * g   (fp32 out).
// R18: revert R17's LDS-free proj+LN fusion (isolated -52us regression:
// 10 L2-latency loads per 16 MFMAs, no pipeline). proj_kernel + ln_kernel
// restored to R16's verified versions. attn unchanged from R16 except a
// redundant fmax(x,-INF) removed from the max tree (bit-identical).
// Verified state being restored: total 272us, attn 122us, absmax 0.03125.

#define Bv 4
#define Nv 2048
#define Hv 16
#define DHv 64
#define Dv 1024
#define NT (Nv / 64)

#define KCONV_BLOCKS 4096
#define WCONV_BLOCKS 512
#define VT_BLOCKS 2048

#define L2E 1.44269504088896340736f

typedef __attribute__((ext_vector_type(8))) short short8;
typedef __attribute__((ext_vector_type(4))) float floatx4;

// bf16 pair pack, round-half-up (+0x8000 then take high16 via one v_perm_b32).
__device__ inline unsigned pack_bf2(float a, float b) {
    unsigned ua = __builtin_bit_cast(unsigned, a) + 0x8000u;
    unsigned ub = __builtin_bit_cast(unsigned, b) + 0x8000u;
    return __builtin_amdgcn_perm(ub, ua, 0x07060302u);  // [b.hi16 : a.hi16]
}

// Packed f32->bf16x2 convert, RTE (1 VALU instr). dst = [bf16(b) : bf16(a)].
__device__ inline unsigned cvt_pk_bf16(float a, float b) {
    unsigned d;
    asm("v_cvt_pk_bf16_f32 %0, %1, %2" : "=v"(d) : "v"(a), "v"(b));
    return d;
}

// RTE bf16 pair (epilogue, grouped for 8B stores).
__device__ inline unsigned bf2u_rte(float a, float b) {
    unsigned short ua = __builtin_bit_cast(unsigned short, __float2bfloat16(a));
    unsigned short ub = __builtin_bit_cast(unsigned short, __float2bfloat16(b));
    return (unsigned)ua | ((unsigned)ub << 16);
}

// 3-input max; clang fuses nested fmaxf to v_max3_f32 on gfx9+.
__device__ inline float max3f(float a, float b, float c) {
    return fmaxf(fmaxf(a, b), c);
}

__device__ inline void plswap16(unsigned &a, unsigned &b) {
    auto r = __builtin_amdgcn_permlane16_swap(a, b, false, false);
    a = r[0]; b = r[1];
}
__device__ inline void plswap32(unsigned &a, unsigned &b) {
    auto r = __builtin_amdgcn_permlane32_swap(a, b, false, false);
    a = r[0]; b = r[1];
}

// Cross-quad max via permlane self-swap (== shfl_xor 16 then 32).
__device__ inline float redq_max(float x) {
    unsigned a = __builtin_bit_cast(unsigned, x), b = a;
    plswap16(a, b);
    float m = fmaxf(__builtin_bit_cast(float, a), __builtin_bit_cast(float, b));
    unsigned c = __builtin_bit_cast(unsigned, m), d = c;
    plswap32(c, d);
    return fmaxf(__builtin_bit_cast(float, c), __builtin_bit_cast(float, d));
}

// ---------------------------------------------------------------------------
// Fused prep (one launch): K f32->bf16 (4096 blk), W f32->bf16 (512 blk),
// V f32 -> V^T bf16 [b][h][64][2048] (2048 blk). pack_bf2 rounding keeps all
// downstream operand bits identical.
// ---------------------------------------------------------------------------
__global__ __launch_bounds__(256)
void prep_all(const float* __restrict__ K, __hip_bfloat16* __restrict__ Kb,
              const float* __restrict__ W, __hip_bfloat16* __restrict__ Wb,
              const float* __restrict__ v, __hip_bfloat16* __restrict__ vt) {
    __shared__ short T[64][76];   // vtrans scratch (+12 pad)
    int bid = blockIdx.x;
    if (bid < KCONV_BLOCKS + WCONV_BLOCKS) {
        const float* src;
        __hip_bfloat16* dst;
        if (bid < KCONV_BLOCKS) { src = K; dst = Kb; }
        else { src = W; dst = Wb; bid -= KCONV_BLOCKS; }
        int base = (bid * 256 + threadIdx.x) * 8;
        float4 f0 = *(const float4*)(src + base);
        float4 f1 = *(const float4*)(src + base + 4);
        uint4 u;
        u.x = pack_bf2(f0.x, f0.y);
        u.y = pack_bf2(f0.z, f0.w);
        u.z = pack_bf2(f1.x, f1.y);
        u.w = pack_bf2(f1.z, f1.w);
        *(uint4*)(dst + base) = u;
        return;
    }
    bid -= KCONV_BLOCKS + WCONV_BLOCKS;        // 0..2047
    const int b = bid >> 9;                    // 512 per batch
    const int rem = bid & 511;
    const int h = rem >> 5;                    // 16 heads
    const int n0 = (rem & 31) * 64;            // 32 n-tiles
    const int t = threadIdx.x;
    const int ir = t >> 4;
    const int d4 = (t & 15) * 4;
#pragma unroll
    for (int pass = 0; pass < 4; ++pass) {
        int n = pass * 16 + ir;
        float4 f = *(const float4*)(v + ((size_t)b * Nv + n0 + n) * Dv + h * DHv + d4);
        T[d4 + 0][n] = (short)(pack_bf2(f.x, f.x) & 0xffffu);
        T[d4 + 1][n] = (short)(pack_bf2(f.y, f.y) & 0xffffu);
        T[d4 + 2][n] = (short)(pack_bf2(f.z, f.z) & 0xffffu);
        T[d4 + 3][n] = (short)(pack_bf2(f.w, f.w) & 0xffffu);
    }
    __syncthreads();
    const int d = t >> 2, kg = (t & 3) * 16;
    unsigned u[8];
#pragma unroll
    for (int i = 0; i < 8; ++i)
        u[i] = (unsigned)(unsigned short)T[d][kg + 2 * i] |
               ((unsigned)(unsigned short)T[d][kg + 2 * i + 1] << 16);
    __hip_bfloat16* op = vt + ((size_t)(b * Hv + h) * DHv + d) * Nv + n0 + kg;
    *(uint4*)op = *(uint4*)&u[0];
    *(uint4*)(op + 8) = *(uint4*)&u[4];
}

// ---------------------------------------------------------------------------
// MFMA flash attention, prep-fed, O^T accumulation. QBLK=64: block = 256 thr
// (4 waves) = 64 queries of one (b,h); wave owns 16 queries (lane = query).
// K / V^T staged via global_load_lds w16 (source-side inverse XOR swizzle).
// Softmax cross-lane via permlane; alpha/linv lane-local (O^T). l computed
// by ones-row MFMA; P packed with v_cvt_pk_bf16_f32.
// ---------------------------------------------------------------------------
__global__ __launch_bounds__(256, 8)
void attn_mfma_pre(const float* __restrict__ q,
                   const __hip_bfloat16* __restrict__ Kb,
                   const __hip_bfloat16* __restrict__ Vtb,
                   __hip_bfloat16* __restrict__ out) {
    __shared__ __align__(16) short Kt[2][64 * 64];   // 16 KB
    __shared__ __align__(16) short Vt[2][64 * 64];   // 16 KB (V^T: rows = d)

    const int t = threadIdx.x;
    const int wave = t >> 6, lane = t & 63;
    const int quad = lane >> 4, lr = lane & 15;
    const int b = blockIdx.z;
    // bijective XCD swizzle over (qtile,head): same-h blocks -> same XCD.
    const int lid2 = blockIdx.y * 32 + blockIdx.x;   // 0..511
    const int xcd = lid2 & 7, jj = lid2 >> 3;        // jj 0..63
    const int h = xcd * 2 + (jj >> 5);
    const int q0 = (jj & 31) * 64;
    const size_t qbh = ((size_t)b * Nv) * Dv + h * DHv;
    const __hip_bfloat16* kb = Kb + (size_t)b * Nv * Dv + h * DHv;
    const __hip_bfloat16* vtb = Vtb + (size_t)(b * Hv + h) * DHv * Nv;

    const int srow = lane >> 3;   // row within 8-row chunk
    const int sg = lane & 7;      // stored group
    auto stage = [&](int buf, int k0) {
#pragma unroll
        for (int c = 0; c < 2; ++c) {
            int blk = wave * 2 + c;          // 0..7, wave-uniform
            int r = blk * 8 + srow;
            int g = sg ^ (r & 7);            // inverse swizzle on source
            __builtin_amdgcn_global_load_lds(
                (const __attribute__((address_space(1))) unsigned*)(const void*)
                    (kb + (size_t)(k0 + r) * Dv + g * 8),
                (__attribute__((address_space(3))) unsigned*)(void*)&Kt[buf][blk * 512],
                16, 0, 0);
            __builtin_amdgcn_global_load_lds(
                (const __attribute__((address_space(1))) unsigned*)(const void*)
                    (vtb + (size_t)r * Nv + k0 + g * 8),
                (__attribute__((address_space(3))) unsigned*)(void*)&Vt[buf][blk * 512],
                16, 0, 0);
        }
    };

    stage(0, 0);   // K/V tile-0 DMA in flight first

    // ---- Q fragments direct from global (once), scale 0.125 exact ----
    short8 qfrag[2];   // [kh]: Q[q = q0+wave*16+lr][d = 32kh+8quad+j]
#pragma unroll
    for (int kh = 0; kh < 2; ++kh) {
        int row = q0 + wave * 16 + lr;
        const float* qp = q + qbh + (size_t)row * Dv + kh * 32 + quad * 8;
        float4 f0 = *(const float4*)qp;
        float4 f1 = *(const float4*)(qp + 4);
        int4 qi;
        qi.x = (int)pack_bf2(f0.x * 0.125f, f0.y * 0.125f);
        qi.y = (int)pack_bf2(f0.z * 0.125f, f0.w * 0.125f);
        qi.z = (int)pack_bf2(f1.x * 0.125f, f1.y * 0.125f);
        qi.w = (int)pack_bf2(f1.z * 0.125f, f1.w * 0.125f);
        qfrag[kh] = __builtin_bit_cast(short8, qi);
    }

    // ones-row A-fragment: A[m][k] = (m==0) ? 1.0bf16 : 0. m = lane&15.
    short8 ones_f;
    {
        unsigned w = (lr == 0) ? 0x3F803F80u : 0u;
        int4 oi = {(int)w, (int)w, (int)w, (int)w};
        ones_f = __builtin_bit_cast(short8, oi);
    }

    floatx4 o_acc[4] = {};           // O^T: [td]: O[q=lr][d=16td+4quad+r]
    floatx4 lsum = {};               // lsum[0] on lanes 0-15 = l(query=lr)
    float mrow = -INFINITY;          // per-query (lane-local, lr)

#pragma unroll 2
    for (int it = 0; it < NT; ++it) {
        const int cur = it & 1;                  // compile-time under unroll 2
        __syncthreads();                         // vmcnt drained: buf[cur] staged
        if (it + 1 < NT) stage(1 - cur, (it + 1) * 64);   // latency hidden by compute

        // ---- S^T = K·Q^T ----
        floatx4 s_acc[4] = {};
        __builtin_amdgcn_s_setprio(1);
#pragma unroll
        for (int tt = 0; tt < 4; ++tt) {
            int row = tt * 16 + lr;
            short8 kf0 = *(const short8*)&Kt[cur][row * 64 + ((quad ^ (lr & 7)) << 3)];
            short8 kf1 = *(const short8*)&Kt[cur][row * 64 + (((4 + quad) ^ (lr & 7)) << 3)];
            s_acc[tt] = __builtin_amdgcn_mfma_f32_16x16x32_bf16(kf0, qfrag[0], s_acc[tt], 0, 0, 0);
            s_acc[tt] = __builtin_amdgcn_mfma_f32_16x16x32_bf16(kf1, qfrag[1], s_acc[tt], 0, 0, 0);
        }
        __builtin_amdgcn_s_setprio(0);

        // ---- online softmax (defer-max) + P pack ----
        float m0 = max3f(s_acc[0][0], s_acc[0][1], s_acc[0][2]);
        float m1 = max3f(s_acc[0][3], s_acc[1][0], s_acc[1][1]);
        float m2 = max3f(s_acc[1][2], s_acc[1][3], s_acc[2][0]);
        float m3 = max3f(s_acc[2][1], s_acc[2][2], s_acc[2][3]);
        float m4 = max3f(s_acc[3][0], s_acc[3][1], s_acc[3][2]);
        float m5 = max3f(m0, m1, s_acc[3][3]);
        float tmax = redq_max(fmaxf(m5, max3f(m2, m3, m4)));
        // defer-max: only rescale when some query's max grew past THR=8.
        if (!__all(tmax <= mrow + 8.0f)) {
            float mnew = fmaxf(mrow, tmax);
            float alpha = __expf(mrow - mnew);   // first tile: exp(-inf)=0
            mrow = mnew;
            lsum[0] *= alpha;                    // lane-local (lanes 0-15 carry l)
#pragma unroll
            for (int td = 0; td < 4; ++td)
#pragma unroll
                for (int r2 = 0; r2 < 4; ++r2) o_acc[td][r2] *= alpha;  // lane-local
        }
        float negmc = -(mrow * L2E);
        unsigned p2[8];
#pragma unroll
        for (int tt = 0; tt < 4; ++tt) {
            float p0 = __builtin_amdgcn_exp2f(__builtin_fmaf(s_acc[tt][0], L2E, negmc));
            float p1 = __builtin_amdgcn_exp2f(__builtin_fmaf(s_acc[tt][1], L2E, negmc));
            float pa = __builtin_amdgcn_exp2f(__builtin_fmaf(s_acc[tt][2], L2E, negmc));
            float pb = __builtin_amdgcn_exp2f(__builtin_fmaf(s_acc[tt][3], L2E, negmc));
            p2[tt * 2 + 0] = cvt_pk_bf16(p0, p1);
            p2[tt * 2 + 1] = cvt_pk_bf16(pa, pb);
        }

        // ---- PV as O^T += V^T·P^T: mfma(V_frag, P_frag). P-gather per pair
        // (x,y): swap32 -> a=[x.lo,y.lo] b=[x.hi,y.hi]; swap16 ->
        // a=[x0,x2,y0,y2] b=[x1,x3,y1,y3] == srcA/srcB words.
        // l rides the MFMA pipe: lsum += ones_row . P. ----
#pragma unroll
        for (int kh = 0; kh < 2; ++kh) {
            int tlo = 4 * kh, thi = 4 * kh + 2;
            unsigned a0 = p2[tlo + 0], b0 = p2[thi + 0];
            unsigned a1 = p2[tlo + 1], b1 = p2[thi + 1];
            plswap32(a0, b0);
            plswap16(a0, b0);
            plswap32(a1, b1);
            plswap16(a1, b1);
            int4 afi;
            afi.x = (int)a0;
            afi.y = (int)a1;
            afi.z = (int)b0;
            afi.w = (int)b1;
            short8 af = __builtin_bit_cast(short8, afi);
            __builtin_amdgcn_s_setprio(1);
#pragma unroll
            for (int td = 0; td < 4; ++td) {
                int d = td * 16 + lr;
                short8 vf = *(const short8*)&Vt[cur][d * 64 + (((kh * 4 + quad) ^ (lr & 7)) << 3)];
                o_acc[td] = __builtin_amdgcn_mfma_f32_16x16x32_bf16(vf, af, o_acc[td], 0, 0, 0);
            }
            lsum = __builtin_amdgcn_mfma_f32_16x16x32_bf16(ones_f, af, lsum, 0, 0, 0);
            __builtin_amdgcn_s_setprio(0);
        }
    }

    // ---- epilogue (O^T): lane owns query q = q0+wave*16+lr.
    // l(q) lives in lsum[0] of lane q (quad 0); broadcast via one shfl. ----
    {
        float linv = __shfl(1.f / lsum[0], lr);
        int qrow = q0 + wave * 16 + lr;
        __hip_bfloat16* op = out + ((size_t)(b * Nv + qrow)) * Dv + h * DHv + quad * 4;
#pragma unroll
        for (int td = 0; td < 4; ++td) {
            uint2 w;
            w.x = bf2u_rte(o_acc[td][0] * linv, o_acc[td][1] * linv);
            w.y = bf2u_rte(o_acc[td][2] * linv, o_acc[td][3] * linv);
            *(uint2*)(op + td * 16) = w;
        }
    }
}

// ---------------------------------------------------------------------------
// Stage 2 (R16-verified): C = A @ Wb^T. m97-structure: 128x128 tile, BK=64,
// double-buffered LDS, global_load_lds w16, XOR-swizzled (row&7) 128B rows.
// Bijective XCD grouping: 8 bn-blocks sharing an A-panel land on one XCD.
// ---------------------------------------------------------------------------
__global__ __launch_bounds__(256)
void proj_kernel(const __hip_bfloat16* __restrict__ A,
                 const __hip_bfloat16* __restrict__ Wb,
                 float* __restrict__ C) {
    __shared__ __align__(16) short As[2][128 * 64];  // 32 KB
    __shared__ __align__(16) short Ws[2][128 * 64];  // 32 KB

    const int t = threadIdx.x;
    const int wave = t >> 6, lane = t & 63;
    const int quad = lane >> 4, lr = lane & 15;
    const int wm = wave >> 1, wn = wave & 1;
    const int bx = blockIdx.x;                 // 0..511
    const int xcd = bx & 7, j = bx >> 3;       // j 0..63
    const int bm = (xcd * 8 + (j >> 3)) * 128;
    const int bn = (j & 7) * 128;

    floatx4 acc[4][4] = {};   // [mb][nb]

    auto stage = [&](int buf, int k0) {
#pragma unroll
        for (int c = 0; c < 4; ++c) {
            const int blk = c * 4 + wave;             // 0..15, wave-uniform
            const int r = blk * 8 + (lane >> 3);
            const int g = (lane & 7) ^ (r & 7);
            const __hip_bfloat16* ga = A + (size_t)(bm + r) * Dv + k0 + g * 8;
            const __hip_bfloat16* gw = Wb + (size_t)(bn + r) * Dv + k0 + g * 8;
            __builtin_amdgcn_global_load_lds(
                (const __attribute__((address_space(1))) unsigned int*)(const void*)ga,
                (__attribute__((address_space(3))) unsigned int*)(void*)&As[buf][blk * 512],
                16, 0, 0);
            __builtin_amdgcn_global_load_lds(
                (const __attribute__((address_space(1))) unsigned int*)(const void*)gw,
                (__attribute__((address_space(3))) unsigned int*)(void*)&Ws[buf][blk * 512],
                16, 0, 0);
        }
    };

    stage(0, 0);

#pragma unroll 2
    for (int it = 0; it < Dv / 64; ++it) {
        const int cur = it & 1;
        __syncthreads();                              // drains vmcnt: buf[cur] staged
        if (it + 1 < Dv / 64) stage(1 - cur, (it + 1) * 64);   // overlaps compute

#pragma unroll
        for (int ks = 0; ks < 2; ++ks) {
            short8 af[4];
#pragma unroll
            for (int mb = 0; mb < 4; ++mb) {
                int row = wm * 64 + mb * 16 + lr;
                af[mb] = *(const short8*)&As[cur][row * 64 + (((ks * 4 + quad) ^ (lr & 7)) << 3)];
            }
#pragma unroll
            for (int nb = 0; nb < 4; ++nb) {
                int row = wn * 64 + nb * 16 + lr;
                short8 bf = *(const short8*)&Ws[cur][row * 64 + (((ks * 4 + quad) ^ (lr & 7)) << 3)];
#pragma unroll
                for (int mb = 0; mb < 4; ++mb)
                    acc[mb][nb] = __builtin_amdgcn_mfma_f32_16x16x32_bf16(af[mb], bf, acc[mb][nb], 0, 0, 0);
            }
        }
    }

    // C/D layout: col = lane&15, row = quad*4 + reg
#pragma unroll
    for (int mb = 0; mb < 4; ++mb)
#pragma unroll
        for (int nb = 0; nb < 4; ++nb) {
            int row = bm + wm * 64 + mb * 16 + quad * 4;
            int col = bn + wn * 64 + nb * 16 + lr;
#pragma unroll
            for (int r = 0; r < 4; ++r)
                C[(size_t)(row + r) * Dv + col] = acc[mb][nb][r];
        }
}

// ---------------------------------------------------------------------------
// Stage 3 (R16-verified): LayerNorm in place on d_out (fp32). eps=1e-5.
// ---------------------------------------------------------------------------
__global__ __launch_bounds__(256)
void ln_kernel(float* __restrict__ C,
               const float* __restrict__ g) {
    const int row = blockIdx.x;
    const int t = threadIdx.x;
    const int wave = t >> 6, lane = t & 63;

    float* rp = C + (size_t)row * Dv;
    float4 x = *(const float4*)(rp + t * 4);

    float s = x.x + x.y + x.z + x.w;
    float sq = x.x * x.x + x.y * x.y + x.z * x.z + x.w * x.w;
#pragma unroll
    for (int off = 32; off >= 1; off >>= 1) {
        s += __shfl_xor(s, off);
        sq += __shfl_xor(sq, off);
    }
    __shared__ float ss[4], ssq[4];
    if (lane == 0) { ss[wave] = s; ssq[wave] = sq; }
    __syncthreads();
    s = ss[0] + ss[1] + ss[2] + ss[3];
    sq = ssq[0] + ssq[1] + ssq[2] + ssq[3];

    const float rn = 1.f / (float)Dv;
    float mean = s * rn;
    float var = sq * rn - mean * mean;
    float inv = rsqrtf(var + 1e-5f);

    float4 gv = *(const float4*)(g + t * 4);

    float4 o;
    o.x = (x.x - mean) * inv * gv.x;
    o.y = (x.y - mean) * inv * gv.y;
    o.z = (x.z - mean) * inv * gv.z;
    o.w = (x.w - mean) * inv * gv.w;
    *(float4*)(rp + t * 4) = o;
}

// ---------------------------------------------------------------------------
extern "C" void kernel_launch(void* const* d_in, const int* in_sizes, int n_in,
                              void* d_out, int out_size, void* d_ws, size_t ws_size,
                              hipStream_t stream) {
    const float* q = (const float*)d_in[0];
    const float* k = (const float*)d_in[1];
    const float* v = (const float*)d_in[2];
    const float* W = (const float*)d_in[3];
    const float* g = (const float*)d_in[4];
    float* out = (float*)d_out;

    const size_t attnB = (size_t)Bv * Nv * Dv * 2;       // 16 MiB bf16 attn out
    const size_t wbB = (size_t)Dv * Dv * 2;              // 2 MiB bf16 W
    const size_t kbB = (size_t)Bv * Nv * Dv * 2;         // 16 MiB bf16 K

    __hip_bfloat16* attn = (__hip_bfloat16*)d_ws;
    __hip_bfloat16* Wb = (__hip_bfloat16*)((char*)d_ws + attnB);
    __hip_bfloat16* Kb = (__hip_bfloat16*)((char*)d_ws + attnB + wbB);
    __hip_bfloat16* Vtb = (__hip_bfloat16*)((char*)d_ws + attnB + wbB + kbB);

    prep_all<<<KCONV_BLOCKS + WCONV_BLOCKS + VT_BLOCKS, 256, 0, stream>>>(k, Kb, W, Wb, v, Vtb);
    attn_mfma_pre<<<dim3(32, 16, Bv), 256, 0, stream>>>(q, Kb, Vtb, attn);
    proj_kernel<<<512, 256, 0, stream>>>(attn, Wb, out);
    ln_kernel<<<Bv * Nv, 256, 0, stream>>>(out, g);
}